// Round 3
// baseline (327.464 us; speedup 1.0000x reference)
//
#include <hip/hip_runtime.h>
#include <hip/hip_bf16.h>
#include <math.h>

// ImageTokenization: conv3x3(64->64)+BN+GELU -> patches(masked) -> proj GEMM(2304->768)+GELU
// Inputs fp32 (proven round 1 vs 2), outputs fp32; compute in bf16 MFMA (tolerance 8*2^-8).
// d_out (fp32) = [tokens 8192x768][patches 8192x2304].

typedef unsigned short u16;
typedef __bf16 bf16x8 __attribute__((ext_vector_type(8)));
typedef float f32x4 __attribute__((ext_vector_type(4)));

#define NFRM 32
#define CH 64
#define HW 96
#define HWP 98
#define KP 2304
#define DIMN 768
#define MTOK 8192
#define TOKN (MTOK * DIMN)          // 6,291,456 floats
#define NPAT (MTOK * KP)            // 18,874,368 floats
// ws layout (u16 units): [xhwc 19,668,992 | bp 36,864 | pw 1,769,472]; xhwc reused as A-bf16
#define XHWC_ELEMS ((size_t)NFRM * HWP * HWP * CH)
#define BP_OFF XHWC_ELEMS
#define PW_OFF (BP_OFF + 36864)

static __device__ __forceinline__ u16 f2b(float f) {
  unsigned u = __builtin_bit_cast(unsigned, f);
  u += 0x7fffu + ((u >> 16) & 1u);
  return (u16)(u >> 16);
}
static __device__ __forceinline__ float gelu_f(float x) {
  return 0.5f * x * (1.0f + erff(x * 0.7071067811865476f));
}

// -------- kernel 1: x[32][64][96][96] fp32 -> xhwc[32][98][98][64] bf16 (halo pre-zeroed) ----
__global__ __launch_bounds__(256) void k_transpose(const float* __restrict__ x,
                                                   u16* __restrict__ xhwc) {
  __shared__ u16 tile[96 * 66];  // [w][ci], stride 66 breaks bank collisions
  const int f = blockIdx.x / 96, h = blockIdx.x % 96;
  const int t = threadIdx.x;
  const float* xp = x + (size_t)f * CH * HW * HW + (size_t)h * HW;
#pragma unroll
  for (int k = 0; k < 6; ++k) {
    int e = (k * 256 + t) * 4;
    int ci = e / 96, w = e % 96;
    float4 v = *(const float4*)(xp + (size_t)ci * (HW * HW) + w);
    tile[(w + 0) * 66 + ci] = f2b(v.x);
    tile[(w + 1) * 66 + ci] = f2b(v.y);
    tile[(w + 2) * 66 + ci] = f2b(v.z);
    tile[(w + 3) * 66 + ci] = f2b(v.w);
  }
  __syncthreads();
  u16* op = xhwc + ((size_t)(f * HWP + h + 1) * HWP + 1) * CH;
#pragma unroll
  for (int k = 0; k < 12; ++k) {
    int e2 = (k * 256 + t) * 2;
    int w = e2 >> 6, ci = e2 & 63;
    *(unsigned*)(op + e2) = *(const unsigned*)(&tile[w * 66 + ci]);
  }
}

// -------- kernel 2: conv_w[co][ci][3][3] fp32 -> bp[co][tap*64+ci] bf16 --------
__global__ __launch_bounds__(256) void k_bpack(const float* __restrict__ w,
                                               u16* __restrict__ bp) {
  int e = blockIdx.x * 256 + threadIdx.x;  // < 36864
  int co = e / 576, r = e - co * 576, tap = r >> 6, ci = r & 63;
  bp[e] = f2b(w[(co * 64 + ci) * 9 + tap]);
}

// -------- kernel 3: proj_w fp32 -> bf16 --------
__global__ __launch_bounds__(256) void k_pw(const float* __restrict__ pw,
                                            u16* __restrict__ dst) {
  int e = (blockIdx.x * 256 + threadIdx.x) * 4;  // < 1,769,472
  float4 v = *(const float4*)(pw + e);
  ushort4 o;
  o.x = f2b(v.x); o.y = f2b(v.y); o.z = f2b(v.z); o.w = f2b(v.w);
  *(ushort4*)(dst + e) = o;
}

// -------- kernel 4: implicit-GEMM conv + BN + GELU + mask -> patches (fp32) --------
// M = patch-ordered pixel idx (n*36+i*6+j), N = co(64), K = tap*64+ci.
__global__ __launch_bounds__(256) void k_conv(
    const u16* __restrict__ xhwc, const u16* __restrict__ bw,
    const float* __restrict__ cb, const float* __restrict__ gma,
    const float* __restrict__ bta, const float* __restrict__ mu,
    const float* __restrict__ var, const float* __restrict__ msk,
    float* __restrict__ pout) {
  __shared__ u16 As[128 * 72];
  __shared__ u16 Bs[64 * 72];
  const int f = blockIdx.x / 72;
  const int m0 = (blockIdx.x % 72) * 128;
  const int t = threadIdx.x;
  const int wv = t >> 6, l = t & 63, quad = l >> 4, lm = l & 15;

  const int r = t >> 1, c0 = (t & 1) * 32;
  const int mg = m0 + r;
  const int np = mg / 36, ii = mg - np * 36;
  const int hb = (np >> 4) * 6 + ii / 6;
  const int wb = (np & 15) * 6 + (ii % 6);
  const u16* xf = xhwc + (size_t)f * (HWP * HWP * CH);
  const int bco = t >> 2, bc = (t & 3) * 16;

  f32x4 acc[2][4];
#pragma unroll
  for (int s = 0; s < 2; ++s)
#pragma unroll
    for (int u = 0; u < 4; ++u) acc[s][u] = (f32x4){0.f, 0.f, 0.f, 0.f};

  for (int tap = 0; tap < 9; ++tap) {
    const int di = tap / 3, dj = tap - di * 3;
    __syncthreads();
    const u16* src = xf + ((hb + di) * HWP + (wb + dj)) * CH + c0;
    u16* dA = &As[r * 72 + c0];
    *(uint4*)(dA + 0) = *(const uint4*)(src + 0);
    *(uint4*)(dA + 8) = *(const uint4*)(src + 8);
    *(uint4*)(dA + 16) = *(const uint4*)(src + 16);
    *(uint4*)(dA + 24) = *(const uint4*)(src + 24);
    const u16* bsrc = bw + bco * 576 + tap * 64 + bc;
    u16* dB = &Bs[bco * 72 + bc];
    *(uint4*)(dB + 0) = *(const uint4*)(bsrc + 0);
    *(uint4*)(dB + 8) = *(const uint4*)(bsrc + 8);
    __syncthreads();
#pragma unroll
    for (int ks = 0; ks < 2; ++ks) {
      const int ko = ks * 32 + quad * 8;
      bf16x8 a0 = *(const bf16x8*)&As[(wv * 32 + lm) * 72 + ko];
      bf16x8 a1 = *(const bf16x8*)&As[(wv * 32 + 16 + lm) * 72 + ko];
#pragma unroll
      for (int u = 0; u < 4; ++u) {
        bf16x8 b = *(const bf16x8*)&Bs[(u * 16 + lm) * 72 + ko];
        acc[0][u] = __builtin_amdgcn_mfma_f32_16x16x32_bf16(a0, b, acc[0][u], 0, 0, 0);
        acc[1][u] = __builtin_amdgcn_mfma_f32_16x16x32_bf16(a1, b, acc[1][u], 0, 0, 0);
      }
    }
  }
  const int mwb = m0 + wv * 32;
#pragma unroll
  for (int u = 0; u < 4; ++u) {
    const int co = u * 16 + lm;  // C/D col = lane&15
    const float scv = gma[co] * rsqrtf(var[co] + 1e-5f);
    const float b2v = (cb[co] - mu[co]) * scv + bta[co];
#pragma unroll
    for (int s = 0; s < 2; ++s) {
#pragma unroll
      for (int rg = 0; rg < 4; ++rg) {
        const int ml = mwb + s * 16 + quad * 4 + rg;  // C/D row = quad*4+reg
        const int n = ml / 36, jj = ml - n * 36;
        float v = acc[s][u][rg] * scv + b2v;
        v = gelu_f(v) * msk[jj];
        pout[((size_t)(f * 256 + n) * 64 + co) * 36 + jj] = v;
      }
    }
  }
}

// -------- kernel 5: patches fp32 -> A bf16 (into dead xhwc region) --------
__global__ __launch_bounds__(256) void k_cvt(const float* __restrict__ pat,
                                             u16* __restrict__ abf) {
  int e = (blockIdx.x * 256 + threadIdx.x) * 4;  // < 18,874,368
  float4 v = *(const float4*)(pat + e);
  ushort4 o;
  o.x = f2b(v.x); o.y = f2b(v.y); o.z = f2b(v.z); o.w = f2b(v.w);
  *(ushort4*)(abf + e) = o;
}

// -------- kernel 6: tokens = gelu(A @ proj_w^T + proj_b), fp32 out --------
// M=8192 K=2304 N=768; BM=128 BN=64 BK=32; bn-fastest block order for A L2 reuse.
__global__ __launch_bounds__(256) void k_gemm(const u16* __restrict__ A,
                                              const u16* __restrict__ Bt,
                                              const float* __restrict__ pb,
                                              float* __restrict__ out) {
  __shared__ u16 As[128 * 40];
  __shared__ u16 Bs[64 * 40];
  const int bn = blockIdx.x % 12, bm = blockIdx.x / 12;
  const int m0 = bm * 128, n0 = bn * 64;
  const int t = threadIdx.x, wv = t >> 6, l = t & 63, quad = l >> 4, lm = l & 15;
  const int ar = t >> 2, ac = (t & 3) * 8;

  f32x4 acc[2][4];
#pragma unroll
  for (int s = 0; s < 2; ++s)
#pragma unroll
    for (int u = 0; u < 4; ++u) acc[s][u] = (f32x4){0.f, 0.f, 0.f, 0.f};

  for (int k0 = 0; k0 < KP; k0 += 32) {
    __syncthreads();
    *(uint4*)&As[ar * 40 + ac] = *(const uint4*)&A[(size_t)(m0 + ar) * KP + k0 + ac];
    *(uint4*)&As[(ar + 64) * 40 + ac] =
        *(const uint4*)&A[(size_t)(m0 + ar + 64) * KP + k0 + ac];
    *(uint4*)&Bs[ar * 40 + ac] = *(const uint4*)&Bt[(size_t)(n0 + ar) * KP + k0 + ac];
    __syncthreads();
    const int ko = quad * 8;
    bf16x8 a0 = *(const bf16x8*)&As[(wv * 32 + lm) * 40 + ko];
    bf16x8 a1 = *(const bf16x8*)&As[(wv * 32 + 16 + lm) * 40 + ko];
#pragma unroll
    for (int u = 0; u < 4; ++u) {
      bf16x8 b = *(const bf16x8*)&Bs[(u * 16 + lm) * 40 + ko];
      acc[0][u] = __builtin_amdgcn_mfma_f32_16x16x32_bf16(a0, b, acc[0][u], 0, 0, 0);
      acc[1][u] = __builtin_amdgcn_mfma_f32_16x16x32_bf16(a1, b, acc[1][u], 0, 0, 0);
    }
  }
#pragma unroll
  for (int u = 0; u < 4; ++u) {
    const int n = n0 + u * 16 + lm;
    const float bias = pb[n];
#pragma unroll
    for (int s = 0; s < 2; ++s) {
#pragma unroll
      for (int rg = 0; rg < 4; ++rg) {
        const int m = m0 + wv * 32 + s * 16 + quad * 4 + rg;
        out[(size_t)m * DIMN + n] = gelu_f(acc[s][u][rg] + bias);
      }
    }
  }
}

extern "C" void kernel_launch(void* const* d_in, const int* in_sizes, int n_in,
                              void* d_out, int out_size, void* d_ws, size_t ws_size,
                              hipStream_t stream) {
  const float* x = (const float*)d_in[0];
  const float* conv_w = (const float*)d_in[1];
  const float* conv_b = (const float*)d_in[2];
  const float* bn_gamma = (const float*)d_in[3];
  const float* bn_beta = (const float*)d_in[4];
  const float* bn_mean = (const float*)d_in[5];
  const float* bn_var = (const float*)d_in[6];
  const float* proj_w = (const float*)d_in[7];
  const float* proj_b = (const float*)d_in[8];
  const float* mask = (const float*)d_in[9];
  float* out = (float*)d_out;         // [tokens][patches], fp32
  float* patches = out + TOKN;
  u16* ws = (u16*)d_ws;
  u16* xhwc = ws;                     // later reused as A bf16
  u16* bp = ws + BP_OFF;
  u16* pw = ws + PW_OFF;

  hipMemsetAsync(d_ws, 0, XHWC_ELEMS * sizeof(u16), stream);  // zero halo
  k_transpose<<<NFRM * HW, 256, 0, stream>>>(x, xhwc);
  k_bpack<<<144, 256, 0, stream>>>(conv_w, bp);
  k_pw<<<1728, 256, 0, stream>>>(proj_w, pw);
  k_conv<<<NFRM * 72, 256, 0, stream>>>(xhwc, bp, conv_b, bn_gamma, bn_beta,
                                        bn_mean, bn_var, mask, patches);
  k_cvt<<<18432, 256, 0, stream>>>(patches, xhwc);  // xhwc dead after k_conv
  k_gemm<<<64 * 12, 256, 0, stream>>>(xhwc, pw, proj_b, out);
}